// Round 1
// 214.747 us; speedup vs baseline: 1.0288x; 1.0288x over previous
//
#include <hip/hip_runtime.h>
#include <hip/hip_fp16.h>
#include <cstddef>

// AffinityPropagate: per-pixel normalized 3x3 stencil, 24 steps.
// R6: batch-read the full 10x3 LDS window into registers at the top of each
// step (one ds_read latency window per step instead of eight -- the in-order
// wave previously stalled per row: 3 b32 reads vs ~20cy of FMA cover).
// Dead-wave skip: waves 0/7's rows leave the valid ring for s>=8; they skip
// compute and park at the barrier (-8% inner work).
// Thread = 1 col x 8 rows (tid = g*64 + c; wave = 64 contiguous cols) -> ALL
// LDS traffic is lane-stride-1 b32 (2 lanes/bank = free, m136).
// Launch 1 normalizes weights in-kernel (redundant region reads, L3-absorbed)
// and stores interior packed weights (half8 taps + f32 center) to d_ws;
// launch 2 loads them. 2 dispatches total (precompute folded in).
//
// Tap order: w0=NW w1=N w2=NE w3=W [center] w4=E w5=SW w6=S w7=SE
//
// Ring/frontier: staged halo 13 (66x66), weight halo 12 (64x64 = staged rows/
// cols 1..64, rewritten every step). Valid staged rings after step s: [s,65-s];
// after 12 steps rows/cols 12..53 valid; output tile is 13..52. Out-of-image
// px have all-zero weights -> stay exactly 0 = zero padding.

#define HIMG 480
#define WIMG 640
#define HW   (HIMG * WIMG)
#define BN   8

#define TILE   40
#define TSTEPS 12
#define IH     13                // staged halo
#define WHL    12                // weight halo
#define SW     66                // staged rows/cols
#define PITCH  68                // LDS row pitch (floats)
#define NT     512

#define WS_FRAME_B  ((size_t)BN * HW * 4)            // 9,830,400
#define WS_WA_B     ((size_t)BN * HW * 16)           // 39,321,600
#define WS_WC_B     ((size_t)BN * HW * 4)            // 9,830,400
#define WS_NEED     (WS_FRAME_B + WS_WA_B + WS_WC_B) // 58,982,400

// MODE: 0 = normalize in-kernel + store interior weights to wA/wC
//       1 = load packed weights from wA/wC
//       2 = normalize in-kernel, no store (fallback when ws too small)
template <int MODE>
__global__ __launch_bounds__(NT, 4) void affprop12(
    const float* __restrict__ aff,
    __half2* __restrict__ wA,
    float* __restrict__ wC,
    const float* __restrict__ src,
    float* __restrict__ dst)
{
    __shared__ float fA[SW * PITCH];
    __shared__ float fB[SW * PITCH];

    const int tid = threadIdx.x;
    const int ox  = blockIdx.x * TILE;
    const int oy  = blockIdx.y * TILE;
    const int b   = blockIdx.z;

    const float* __restrict__ sb = src + (size_t)b * HW;
    float*       __restrict__ db = dst + (size_t)b * HW;

    // ---- stage input region [oy-13, oy+53) x [ox-13, ox+53), 0 outside image
    for (int i = tid; i < SW * SW; i += NT) {
        int r  = i / SW;
        int c  = i - r * SW;
        int gy = oy - IH + r;
        int gx = ox - IH + c;
        float v = 0.f;
        if ((unsigned)gy < (unsigned)HIMG && (unsigned)gx < (unsigned)WIMG)
            v = sb[gy * WIMG + gx];
        fA[r * PITCH + c] = v;
    }
    // ---- zero-fill buffer B (deterministic stale rings)
    for (int i = tid; i < SW * PITCH / 4; i += NT)
        *(float4*)&fB[4 * i] = make_float4(0.f, 0.f, 0.f, 0.f);

    // ---- per-thread: weight column c, row group g (8 rows)
    const int c  = tid & 63;          // weight col 0..63
    const int g  = tid >> 6;          // row group 0..7
    const int sc = c + 1;             // staged col of this thread's outputs

    __half2 wv[8][4];   // [row i][tap pair (01)(23)(45)(67)]
    float   wcc[8];     // center weights (f32)

    #pragma unroll
    for (int i = 0; i < 8; ++i) {
        const int gy = oy - WHL + 8 * g + i;
        const int gx = ox - WHL + c;
        const bool in = (unsigned)gy < (unsigned)HIMG && (unsigned)gx < (unsigned)WIMG;
        const size_t idx = (size_t)b * HW + (size_t)gy * WIMG + gx;

        if (MODE == 1) {
            if (in) {
                union { float4 f4; __half2 h[4]; } u;
                u.f4 = *(const float4*)(wA + 4 * idx);
                wv[i][0] = u.h[0]; wv[i][1] = u.h[1];
                wv[i][2] = u.h[2]; wv[i][3] = u.h[3];
                wcc[i] = wC[idx];
            } else {
                __half2 z = __floats2half2_rn(0.f, 0.f);
                wv[i][0] = z; wv[i][1] = z; wv[i][2] = z; wv[i][3] = z;
                wcc[i] = 0.f;
            }
        } else {
            float w[8];
            float s = 0.f;
            if (in) {
                const float* ap = aff + (size_t)b * 8 * HW + (size_t)gy * WIMG + gx;
                #pragma unroll
                for (int k = 0; k < 8; ++k) { w[k] = ap[(size_t)k * HW]; s += fabsf(w[k]); }
            } else {
                #pragma unroll
                for (int k = 0; k < 8; ++k) w[k] = 0.f;
                s = 1.f;
            }
            float rr  = in ? 1.0f / s : 0.f;
            float acc = 0.f;
            #pragma unroll
            for (int k = 0; k < 8; ++k) { w[k] *= rr; acc += w[k]; }

            union { float4 f4; __half2 h[4]; } u;
            u.h[0] = __floats2half2_rn(w[0], w[1]);
            u.h[1] = __floats2half2_rn(w[2], w[3]);
            u.h[2] = __floats2half2_rn(w[4], w[5]);
            u.h[3] = __floats2half2_rn(w[6], w[7]);
            wv[i][0] = u.h[0]; wv[i][1] = u.h[1];
            wv[i][2] = u.h[2]; wv[i][3] = u.h[3];
            wcc[i] = in ? 1.0f - acc : 0.f;

            if (MODE == 0) {
                // store interior weights for launch 2 (each image px interior
                // to exactly one block)
                if ((unsigned)(gy - oy) < (unsigned)TILE &&
                    (unsigned)(gx - ox) < (unsigned)TILE) {
                    *(float4*)(wA + 4 * idx) = u.f4;
                    wC[idx] = wcc[i];
                }
            }
        }
    }
    __syncthreads();

    // ---- 12 fused steps; whole 10x3 window batch-read into registers,
    //      then 8 outputs, then 8 writes. Stride-1 LDS only.
    const float* fin = fA;
    float*       fo  = fB;

    #pragma unroll 1
    for (int s = 0; s < TSTEPS; ++s) {
        // wave-uniform liveness: wave g writes staged rows 8g+1..8g+8; the
        // ring needed after step s is [s+1, 64-s].
        const bool live = (8 * g + 8 >= s + 1) && (8 * g + 1 <= 64 - s);
        if (live) {
            const float* bp = fin + (8 * g) * PITCH + c;   // staged cols sc-1..sc+1
            float t0[10], t1[10], t2[10];
            #pragma unroll
            for (int r = 0; r < 10; ++r) {
                t0[r] = bp[r * PITCH + 0];
                t1[r] = bp[r * PITCH + 1];
                t2[r] = bp[r * PITCH + 2];
            }
            float* wp = fo + (8 * g + 1) * PITCH + sc;
            #pragma unroll
            for (int i = 0; i < 8; ++i) {
                float o = wcc[i] * t1[i + 1]
                    + __low2float (wv[i][0]) * t0[i]        // NW
                    + __high2float(wv[i][0]) * t1[i]        // N
                    + __low2float (wv[i][1]) * t2[i]        // NE
                    + __high2float(wv[i][1]) * t0[i + 1]    // W
                    + __low2float (wv[i][2]) * t2[i + 1]    // E
                    + __high2float(wv[i][2]) * t0[i + 2]    // SW
                    + __low2float (wv[i][3]) * t1[i + 2]    // S
                    + __high2float(wv[i][3]) * t2[i + 2];   // SE
                wp[i * PITCH] = o;
            }
        }
        __syncthreads();
        const float* t = fin; fin = fo; fo = (float*)t;
    }

    // ---- store 40x40 tile (fin == fA after 12 steps)
    for (int i = tid; i < TILE * (TILE / 4); i += NT) {
        int r  = i / (TILE / 4);
        int c4 = (i - r * (TILE / 4)) * 4;
        const float* p = fin + (IH + r) * PITCH + IH + c4;
        float4 v = make_float4(p[0], p[1], p[2], p[3]);
        *(float4*)&db[(size_t)(oy + r) * WIMG + ox + c4] = v;
    }
}

extern "C" void kernel_launch(void* const* d_in, const int* in_sizes, int n_in,
                              void* d_out, int out_size, void* d_ws, size_t ws_size,
                              hipStream_t stream)
{
    const float* aff  = (const float*)d_in[0];
    const float* feat = (const float*)d_in[1];
    float* out = (float*)d_out;

    char* ws = (char*)d_ws;
    float*   wsFrame = (float*)ws;
    __half2* wA      = (__half2*)(ws + WS_FRAME_B);
    float*   wC      = (float*)(ws + WS_FRAME_B + WS_WA_B);

    dim3 blk(NT, 1, 1);
    dim3 grd(WIMG / TILE, HIMG / TILE, BN);   // 16 x 12 x 8 = 1536 blocks

    if (ws_size >= WS_NEED) {
        affprop12<0><<<grd, blk, 0, stream>>>(aff, wA, wC, feat, wsFrame);
        affprop12<1><<<grd, blk, 0, stream>>>(aff, wA, wC, wsFrame, out);
    } else {
        affprop12<2><<<grd, blk, 0, stream>>>(aff, nullptr, nullptr, feat, wsFrame);
        affprop12<2><<<grd, blk, 0, stream>>>(aff, nullptr, nullptr, wsFrame, out);
    }
}